// Round 5
// baseline (6694.997 us; speedup 1.0000x reference)
//
#include <hip/hip_runtime.h>
#include <math.h>

// 3-layer LSTM (H=64, T=512, B=2048, Din=16) fused persistent kernel, R5.
// Structure identical to R4 (3 layer groups x 256 threads, pipelined in time,
// weights in SSA vector values, h broadcast via v_readlane).
// R5 single change: LDS padded to 86016 B via one pool array. With 37888 B the
// scheduler assumed 4 blocks/CU could be resident -> occupancy target ~6
// waves/EU -> 84-VGPR cap -> weights spilled to scratch (11.5 GB/dispatch HBM
// re-reads). At >80 KB only 1 block (12 waves = 3/SIMD) fits, so the budget
// becomes ~170 VGPRs. Runtime occupancy is unchanged: grid=256 = 1 block/CU.

#define TSTEPS 512
#define HID    64
#define G4     256   // 4*HID
#define DIN0   16
#define CB     8     // batch rows per block
#define NTHREADS 768
#define BATCH  2048

// LDS pool (floats): xs @0 [2][8][16]=256 | h0 @256, h1 @1280, h2 @2304
// ([2][8][64]=1024 each) | gates @3328 [3][8][256]=6144 | used=9472,
// padded to 21504 floats = 86016 B  (>80 KB -> 1 block/CU in compiler model)
#define LDSF   21504
#define XS_O   0
#define H0_O   256
#define H1_O   1280
#define H2_O   2304
#define GT_O   3328

typedef float f16v __attribute__((ext_vector_type(16)));

__device__ __forceinline__ float sigm(float z) {
    return 1.0f / (1.0f + __expf(-z));
}
__device__ __forceinline__ float tanh_fast(float z) {
    z = fminf(15.0f, fmaxf(-15.0f, z));
    const float e = __expf(2.0f * z);
    return (e - 1.0f) / (e + 1.0f);
}
// wave-uniform broadcast of lane k's value (v_readlane -> SGPR operand to FMA)
__device__ __forceinline__ float bcast(float v, int k) {
    return __int_as_float(__builtin_amdgcn_readlane(__float_as_int(v), k));
}

// acc_b += h[b][KB+k_] * W[k_]  for b in 0..7, k_ in 0..15
#define DOT16(W, KB) do {                                          \
    _Pragma("unroll")                                              \
    for (int k_ = 0; k_ < 16; ++k_) {                              \
        const float w_ = (W)[k_];                                  \
        acc0 = fmaf(bcast(v0, (KB) + k_), w_, acc0);               \
        acc1 = fmaf(bcast(v1, (KB) + k_), w_, acc1);               \
        acc2 = fmaf(bcast(v2, (KB) + k_), w_, acc2);               \
        acc3 = fmaf(bcast(v3, (KB) + k_), w_, acc3);               \
        acc4 = fmaf(bcast(v4, (KB) + k_), w_, acc4);               \
        acc5 = fmaf(bcast(v5, (KB) + k_), w_, acc5);               \
        acc6 = fmaf(bcast(v6, (KB) + k_), w_, acc6);               \
        acc7 = fmaf(bcast(v7, (KB) + k_), w_, acc7);               \
    }                                                              \
} while (0)

#define LOADV(SRC, STRIDE, IDX)                                    \
    v0 = (SRC)[0 * (STRIDE) + (IDX)];                              \
    v1 = (SRC)[1 * (STRIDE) + (IDX)];                              \
    v2 = (SRC)[2 * (STRIDE) + (IDX)];                              \
    v3 = (SRC)[3 * (STRIDE) + (IDX)];                              \
    v4 = (SRC)[4 * (STRIDE) + (IDX)];                              \
    v5 = (SRC)[5 * (STRIDE) + (IDX)];                              \
    v6 = (SRC)[6 * (STRIDE) + (IDX)];                              \
    v7 = (SRC)[7 * (STRIDE) + (IDX)];

__global__
__attribute__((amdgpu_flat_work_group_size(NTHREADS, NTHREADS),
               amdgpu_waves_per_eu(3, 3)))
void lstm3_fused(
    const float* __restrict__ x,      // [B, T, 16]
    const float* __restrict__ Wih0,   // [256,16]
    const float* __restrict__ Whh0,   // [256,64]
    const float* __restrict__ bih0,   // [256]
    const float* __restrict__ bhh0,   // [256]
    const float* __restrict__ Wih1,   // [256,64]
    const float* __restrict__ Whh1,   // [256,64]
    const float* __restrict__ bih1,
    const float* __restrict__ bhh1,
    const float* __restrict__ Wih2,   // [256,64]
    const float* __restrict__ Whh2,   // [256,64]
    const float* __restrict__ bih2,
    const float* __restrict__ bhh2,
    const float* __restrict__ Wout,   // [7,64]
    const float* __restrict__ bout,   // [7]
    float* __restrict__ out)          // [B,7]
{
    __shared__ __attribute__((aligned(16))) float lds[LDSF];

    const int tid  = threadIdx.x;
    const int grp  = tid >> 8;     // layer group 0..2
    const int r    = tid & 255;    // gate row within layer
    const int lane = tid & 63;
    const int b0   = blockIdx.x * CB;

    // ---- weights as SSA vector values (no alloca -> no scratch) ----
    f16v WH0, WH1, WH2, WH3;   // whh row: 64 floats
    f16v WI0, WI1, WI2, WI3;   // wih row: 64 floats (grp0 uses WI0 only)
    float bias;
    {
        const float* whhp = (grp == 0) ? Whh0 : (grp == 1) ? Whh1 : Whh2;
        const f16v* wp = (const f16v*)(whhp + r * HID);
        WH0 = wp[0]; WH1 = wp[1]; WH2 = wp[2]; WH3 = wp[3];
    }
    if (grp == 0) {
        WI0 = *(const f16v*)(Wih0 + r * DIN0);
        bias = bih0[r] + bhh0[r];
    } else if (grp == 1) {
        const f16v* wp = (const f16v*)(Wih1 + r * HID);
        WI0 = wp[0]; WI1 = wp[1]; WI2 = wp[2]; WI3 = wp[3];
        bias = bih1[r] + bhh1[r];
    } else {
        const f16v* wp = (const f16v*)(Wih2 + r * HID);
        WI0 = wp[0]; WI1 = wp[1]; WI2 = wp[2]; WI3 = wp[3];
        bias = bih2[r] + bhh2[r];
    }

    // ---- zero h double-buffers (both slots), stage x[t=0] ----
    for (int i = tid; i < 3 * 2 * CB * HID; i += NTHREADS)
        lds[H0_O + i] = 0.0f;
    if (tid < 128) {
        lds[XS_O + (tid >> 4) * DIN0 + (tid & 15)] =
            x[(b0 + (tid >> 4)) * (TSTEPS * DIN0) + (tid & 15)];
    }

    float cst0 = 0.0f, cst1 = 0.0f;   // c state: 2 (batch,unit) cells/thread

    __syncthreads();

    for (int it = 0; it < TSTEPS + 2; ++it) {
        const int t = it - grp;                  // this group's timestep
        const bool act = (t >= 0) && (t < TSTEPS);
        const int ps = (it + 1) & 1;             // previous h slot

        // ================= Phase A: gate pre-activations =================
        if (act) {
            float acc0 = bias, acc1 = bias, acc2 = bias, acc3 = bias;
            float acc4 = bias, acc5 = bias, acc6 = bias, acc7 = bias;
            float v0, v1, v2, v3, v4, v5, v6, v7;

            // ---- input-side GEMV (x for grp0, previous layer's h else) ----
            if (grp == 0) {
                const float* src = &lds[XS_O + (t & 1) * CB * DIN0];
                LOADV(src, DIN0, lane & 15)
                DOT16(WI0, 0);
            } else {
                const float* src = (grp == 1) ? &lds[H0_O + ps * CB * HID]
                                              : &lds[H1_O + ps * CB * HID];
                LOADV(src, HID, lane)
                DOT16(WI0, 0);
                DOT16(WI1, 16);
                DOT16(WI2, 32);
                DOT16(WI3, 48);
            }
            // ---- recurrent-side GEMV (own h, previous step) ----
            {
                const float* hs = (grp == 0) ? &lds[H0_O + ps * CB * HID]
                                : (grp == 1) ? &lds[H1_O + ps * CB * HID]
                                             : &lds[H2_O + ps * CB * HID];
                LOADV(hs, HID, lane)
                DOT16(WH0, 0);
                DOT16(WH1, 16);
                DOT16(WH2, 32);
                DOT16(WH3, 48);
            }
            float* gd = &lds[GT_O + grp * (CB * G4)];
            gd[0 * G4 + r] = acc0;  gd[1 * G4 + r] = acc1;
            gd[2 * G4 + r] = acc2;  gd[3 * G4 + r] = acc3;
            gd[4 * G4 + r] = acc4;  gd[5 * G4 + r] = acc5;
            gd[6 * G4 + r] = acc6;  gd[7 * G4 + r] = acc7;
        }
        __syncthreads();

        // ================= Phase B: elementwise update ===================
        if (act) {
            const int u  = r & 63;
            const int bb = r >> 6;     // handles batch rows bb and bb+4
            float* hdst = (grp == 0) ? &lds[H0_O + (it & 1) * CB * HID]
                        : (grp == 1) ? &lds[H1_O + (it & 1) * CB * HID]
                                     : &lds[H2_O + (it & 1) * CB * HID];
            const float* gsrc = &lds[GT_O + grp * (CB * G4)];
            {
                const int b = bb;
                const float gi = gsrc[b * G4 + u];
                const float gf = gsrc[b * G4 + 64 + u];
                const float gg = gsrc[b * G4 + 128 + u];
                const float go = gsrc[b * G4 + 192 + u];
                const float c  = sigm(gf) * cst0 + sigm(gi) * tanh_fast(gg);
                cst0 = c;
                hdst[b * HID + u] = sigm(go) * tanh_fast(c);
            }
            {
                const int b = bb + 4;
                const float gi = gsrc[b * G4 + u];
                const float gf = gsrc[b * G4 + 64 + u];
                const float gg = gsrc[b * G4 + 128 + u];
                const float go = gsrc[b * G4 + 192 + u];
                const float c  = sigm(gf) * cst1 + sigm(gi) * tanh_fast(gg);
                cst1 = c;
                hdst[b * HID + u] = sigm(go) * tanh_fast(c);
            }
        }
        // stage next x tile (group 0's next timestep), hidden under phase B
        if (grp == 0 && r < 128 && (it + 1) < TSTEPS) {
            lds[XS_O + ((it + 1) & 1) * CB * DIN0 + (r >> 4) * DIN0 + (r & 15)] =
                x[(b0 + (r >> 4)) * (TSTEPS * DIN0) + (it + 1) * DIN0 + (r & 15)];
        }
        __syncthreads();
    }

    // ================= head: out = h2[T-1] @ Wout.T + bout ==============
    if (grp == 2 && r < 7 * CB) {
        const int b = r / 7;
        const int o = r % 7;
        float a2 = bout[o];
        const float* h2last = &lds[H2_O + ((TSTEPS + 1) & 1) * CB * HID];
        #pragma unroll
        for (int k = 0; k < HID; ++k)
            a2 = fmaf(h2last[b * HID + k], Wout[o * HID + k], a2);
        out[(b0 + b) * 7 + o] = a2;
    }
}

extern "C" void kernel_launch(void* const* d_in, const int* in_sizes, int n_in,
                              void* d_out, int out_size, void* d_ws, size_t ws_size,
                              hipStream_t stream) {
    const float* x    = (const float*)d_in[0];
    const float* Wih0 = (const float*)d_in[1];
    const float* Whh0 = (const float*)d_in[2];
    const float* bih0 = (const float*)d_in[3];
    const float* bhh0 = (const float*)d_in[4];
    const float* Wih1 = (const float*)d_in[5];
    const float* Whh1 = (const float*)d_in[6];
    const float* bih1 = (const float*)d_in[7];
    const float* bhh1 = (const float*)d_in[8];
    const float* Wih2 = (const float*)d_in[9];
    const float* Whh2 = (const float*)d_in[10];
    const float* bih2 = (const float*)d_in[11];
    const float* bhh2 = (const float*)d_in[12];
    const float* Wout = (const float*)d_in[13];
    const float* bout = (const float*)d_in[14];
    float* out = (float*)d_out;

    lstm3_fused<<<dim3(BATCH / CB), dim3(NTHREADS), 0, stream>>>(
        x, Wih0, Whh0, bih0, bhh0,
        Wih1, Whh1, bih1, bhh1,
        Wih2, Whh2, bih2, bhh2,
        Wout, bout, out);
}

// Round 6
// 1688.749 us; speedup vs baseline: 3.9645x; 3.9645x over previous
//
#include <hip/hip_runtime.h>
#include <math.h>

// 3-layer LSTM (H=64, T=512, B=2048, Din=16), R6: layer-sequential MFMA.
// 3 stream-ordered dispatches (layer 0,1,2; head fused into layer 2).
// Per block: 1024 threads = 16 waves, CB=8 batch rows, grid 256 (1 block/CU).
// Each wave owns one 16-column N-tile of the 256 gate rows; its weight
// B-fragments (bf16 hi+lo, ih+hh) live in 32 VGPRs for the whole kernel --
// total register need ~62, under the 84-VGPR cap the compiler insists on
// (R1-R5: every attempt to raise it failed; this design doesn't need to).
// Precision: 3-term bf16 split (whi*hhi + whi*hlo + wlo*hhi) on
// mfma_f32_16x16x32_bf16, fp32 accum, fp32 c/h state.
// Inter-layer h sequence: d_ws as [T][B][64] u32 (bf16 hi | lo<<16), 268 MB,
// overwritten in place by each layer (read tile t before writing tile t).

#define T_STEPS 512
#define BATCH   2048
#define HID     64
#define NG      256
#define CB      8
#define NTHR    1024

typedef __attribute__((ext_vector_type(8))) short bf16x8;
typedef __attribute__((ext_vector_type(4))) float f32x4;

__device__ __forceinline__ float sigm(float z) { return 1.0f / (1.0f + __expf(-z)); }
__device__ __forceinline__ float tanh_f(float z) {
    z = fminf(15.0f, fmaxf(-15.0f, z));
    const float e = __expf(2.0f * z);
    return (e - 1.0f) / (e + 1.0f);
}
// truncate f32 -> bf16 (lo term captures the remainder; no rounding needed)
__device__ __forceinline__ short tb(float v) { return (short)(__float_as_uint(v) >> 16); }
__device__ __forceinline__ float fb(short h) {
    return __uint_as_float(((unsigned)(unsigned short)h) << 16);
}
// XOR-swizzled byte address of 16B unit u8 (0..7) in an [8][64]-bf16 plane
__device__ __forceinline__ int paddr(int row, int u8) {
    row &= 7;
    return row * 128 + ((u8 ^ row) << 4);
}
// write one bf16 element (row, k) into a swizzled plane
__device__ __forceinline__ void pwr(short* plane, int row, int k, short v) {
    *(short*)((char*)plane + paddr(row, k >> 3) + (k & 7) * 2) = v;
}
__device__ __forceinline__ bf16x8 prd(const short* plane, int row, int u8) {
    return *(const bf16x8*)((const char*)plane + paddr(row, u8));
}

__global__ __launch_bounds__(NTHR) void lstm_layer(
    const float* __restrict__ x0,    // layer0 input [B][T][16] fp32, or null
    unsigned*    __restrict__ hseq,  // [T][B][64] packed bf16 hi|lo<<16
    const float* __restrict__ Wih,   // [256][Din]
    const float* __restrict__ Whh,   // [256][64]
    const float* __restrict__ bih,   // [256]
    const float* __restrict__ bhh,   // [256]
    const float* __restrict__ Wout,  // [7][64] (head only)
    const float* __restrict__ bout,  // [7]
    float* __restrict__ out,         // [B][7]
    int Din, int store_h, int do_head)
{
    __shared__ __attribute__((aligned(16))) short xhi[8 * 64], xlo[8 * 64];
    __shared__ __attribute__((aligned(16))) short hhi[8 * 64], hlo[8 * 64];
    __shared__ __attribute__((aligned(16))) float gts[8 * NG];
    __shared__ __attribute__((aligned(16))) float hf[8 * HID];

    const int tid  = threadIdx.x;
    const int lane = tid & 63;
    const int wid  = tid >> 6;          // 0..15: N-tile index
    const int n0   = wid * 16;
    const int ncol = n0 + (lane & 15);  // this lane's gate row (B-frag col)
    const int ksub = (lane >> 4) & 3;   // k-subgroup of 8
    const int b0   = blockIdx.x * CB;

    // ---- weight B-fragments, resident in registers for the whole kernel ----
    bf16x8 BIh[2], BIl[2], BHh[2], BHl[2];
    #pragma unroll
    for (int s = 0; s < 2; ++s) {
        bf16x8 h8 = {0, 0, 0, 0, 0, 0, 0, 0};
        bf16x8 l8 = {0, 0, 0, 0, 0, 0, 0, 0};
        const int k0 = s * 32 + ksub * 8;
        if (k0 < Din) {   // layer0: Din=16 -> only s=0, ksub<2 valid
            const float4 a = *(const float4*)(Wih + ncol * Din + k0);
            const float4 b = *(const float4*)(Wih + ncol * Din + k0 + 4);
            const float v[8] = {a.x, a.y, a.z, a.w, b.x, b.y, b.z, b.w};
            #pragma unroll
            for (int e = 0; e < 8; ++e) {
                h8[e] = tb(v[e]);
                l8[e] = tb(v[e] - fb(h8[e]));
            }
        }
        BIh[s] = h8; BIl[s] = l8;
    }
    #pragma unroll
    for (int s = 0; s < 2; ++s) {
        bf16x8 h8, l8;
        const int k0 = s * 32 + ksub * 8;
        const float4 a = *(const float4*)(Whh + ncol * HID + k0);
        const float4 b = *(const float4*)(Whh + ncol * HID + k0 + 4);
        const float v[8] = {a.x, a.y, a.z, a.w, b.x, b.y, b.z, b.w};
        #pragma unroll
        for (int e = 0; e < 8; ++e) {
            h8[e] = tb(v[e]);
            l8[e] = tb(v[e] - fb(h8[e]));
        }
        BHh[s] = h8; BHl[s] = l8;
    }
    const float biasr = bih[ncol] + bhh[ncol];   // folded into C at writeout

    // ---- zero h/x planes (h(t=0)=0; x cols >= Din stay 0 forever) ----
    for (int i = tid; i < 8 * 64; i += NTHR) {
        xhi[i] = 0; xlo[i] = 0; hhi[i] = 0; hlo[i] = 0;
    }
    __syncthreads();

    // ---- stage input tile t=0 into x planes ----
    if (x0) {
        if (tid < 128) {
            const int b = tid >> 4, k = tid & 15;
            const float v = x0[(b0 + b) * (T_STEPS * 16) + k];
            const short h_ = tb(v);
            pwr(xhi, b, k, h_);
            pwr(xlo, b, k, tb(v - fb(h_)));
        }
    } else if (tid < 512) {
        const int b = tid >> 6, u = tid & 63;
        const unsigned p = hseq[(size_t)0 * BATCH * HID + (b0 + b) * HID + u];
        pwr(xhi, b, u, (short)(p & 0xffff));
        pwr(xlo, b, u, (short)(p >> 16));
    }
    __syncthreads();

    float cst = 0.0f;   // c state (threads < 512: one (b,u) cell each)

    for (int t = 0; t < T_STEPS; ++t) {
        // -- prefetch next input tile (latency hidden under the MFMAs) --
        float pxn = 0.0f; unsigned phn = 0;
        if (t + 1 < T_STEPS) {
            if (x0) {
                if (tid < 128)
                    pxn = x0[(b0 + (tid >> 4)) * (T_STEPS * 16) + (t + 1) * 16 + (tid & 15)];
            } else if (tid < 512) {
                phn = hseq[(size_t)(t + 1) * BATCH * HID + (b0 + (tid >> 6)) * HID + (tid & 63)];
            }
        }

        // -- Phase A: gates[8,256] = [x|h] @ W^T via MFMA, 3-term split --
        f32x4 C = {0.f, 0.f, 0.f, 0.f};
        const int arow = lane & 15;
        #pragma unroll
        for (int s = 0; s < 2; ++s) {
            if (s * 32 < Din) {
                const bf16x8 ah = prd(xhi, arow, s * 4 + ksub);
                const bf16x8 al = prd(xlo, arow, s * 4 + ksub);
                C = __builtin_amdgcn_mfma_f32_16x16x32_bf16(ah, BIh[s], C, 0, 0, 0);
                C = __builtin_amdgcn_mfma_f32_16x16x32_bf16(al, BIh[s], C, 0, 0, 0);
                C = __builtin_amdgcn_mfma_f32_16x16x32_bf16(ah, BIl[s], C, 0, 0, 0);
            }
        }
        #pragma unroll
        for (int s = 0; s < 2; ++s) {
            const bf16x8 ah = prd(hhi, arow, s * 4 + ksub);
            const bf16x8 al = prd(hlo, arow, s * 4 + ksub);
            C = __builtin_amdgcn_mfma_f32_16x16x32_bf16(ah, BHh[s], C, 0, 0, 0);
            C = __builtin_amdgcn_mfma_f32_16x16x32_bf16(al, BHh[s], C, 0, 0, 0);
            C = __builtin_amdgcn_mfma_f32_16x16x32_bf16(ah, BHl[s], C, 0, 0, 0);
        }
        // C writeout: row=(lane>>4)*4+j, col=ncol; rows 8..15 are padding
        #pragma unroll
        for (int j = 0; j < 4; ++j) {
            const int r2 = (lane >> 4) * 4 + j;
            if (r2 < 8) gts[r2 * NG + ncol] = C[j] + biasr;
        }
        __syncthreads();

        // -- Phase B: elementwise LSTM cell, 1 (b,u) cell per thread --
        if (tid < 512) {
            const int b = tid >> 6, u = tid & 63;
            const float gi = gts[b * NG + u];
            const float gf = gts[b * NG + 64 + u];
            const float gg = gts[b * NG + 128 + u];
            const float go = gts[b * NG + 192 + u];
            cst = sigm(gf) * cst + sigm(gi) * tanh_f(gg);
            const float h = sigm(go) * tanh_f(cst);
            const short h_hi = tb(h);
            const short h_lo = tb(h - fb(h_hi));
            pwr(hhi, b, u, h_hi);
            pwr(hlo, b, u, h_lo);
            if (store_h)
                hseq[(size_t)t * BATCH * HID + (b0 + b) * HID + u] =
                    (unsigned)(unsigned short)h_hi | ((unsigned)(unsigned short)h_lo << 16);
            if (do_head && t == T_STEPS - 1) hf[b * HID + u] = h;
            if (t + 1 < T_STEPS && !x0) {
                pwr(xhi, b, u, (short)(phn & 0xffff));
                pwr(xlo, b, u, (short)(phn >> 16));
            }
        }
        if (x0 && t + 1 < T_STEPS && tid < 128) {
            const int b = tid >> 4, k = tid & 15;
            const short h_ = tb(pxn);
            pwr(xhi, b, k, h_);
            pwr(xlo, b, k, tb(pxn - fb(h_)));
        }
        __syncthreads();
    }

    // -- head: out = h2[T-1] @ Wout^T + bout --
    if (do_head && tid < 7 * CB) {
        const int b = tid / 7, o = tid % 7;
        float a = bout[o];
        #pragma unroll
        for (int k = 0; k < HID; ++k)
            a = fmaf(hf[b * HID + k], Wout[o * HID + k], a);
        out[(b0 + b) * 7 + o] = a;
    }
}

extern "C" void kernel_launch(void* const* d_in, const int* in_sizes, int n_in,
                              void* d_out, int out_size, void* d_ws, size_t ws_size,
                              hipStream_t stream) {
    const float* x    = (const float*)d_in[0];
    const float* Wih0 = (const float*)d_in[1];
    const float* Whh0 = (const float*)d_in[2];
    const float* bih0 = (const float*)d_in[3];
    const float* bhh0 = (const float*)d_in[4];
    const float* Wih1 = (const float*)d_in[5];
    const float* Whh1 = (const float*)d_in[6];
    const float* bih1 = (const float*)d_in[7];
    const float* bhh1 = (const float*)d_in[8];
    const float* Wih2 = (const float*)d_in[9];
    const float* Whh2 = (const float*)d_in[10];
    const float* bih2 = (const float*)d_in[11];
    const float* bhh2 = (const float*)d_in[12];
    const float* Wout = (const float*)d_in[13];
    const float* bout = (const float*)d_in[14];
    float* out = (float*)d_out;
    unsigned* hseq = (unsigned*)d_ws;   // needs T*B*64*4 = 268,435,456 B

    const dim3 grid(BATCH / CB), blk(NTHR);
    // layer 0: x (fp32, Din=16) -> hseq
    lstm_layer<<<grid, blk, 0, stream>>>(x, hseq, Wih0, Whh0, bih0, bhh0,
                                         nullptr, nullptr, nullptr, 16, 1, 0);
    // layer 1: hseq -> hseq (in place)
    lstm_layer<<<grid, blk, 0, stream>>>(nullptr, hseq, Wih1, Whh1, bih1, bhh1,
                                         nullptr, nullptr, nullptr, HID, 1, 0);
    // layer 2 + head
    lstm_layer<<<grid, blk, 0, stream>>>(nullptr, hseq, Wih2, Whh2, bih2, bhh2,
                                         Wout, bout, out, HID, 0, 1);
}

// Round 7
// 1530.600 us; speedup vs baseline: 4.3741x; 1.1033x over previous
//
#include <hip/hip_runtime.h>
#include <math.h>

// 3-layer LSTM (H=64, T=512, B=2048, Din=16), R7: layer-sequential MFMA,
// software-pipelined. 3 stream-ordered dispatches (head fused into layer 2).
// Per block: 1024 threads = 16 waves, CB=8 batch rows, grid 256 (1 block/CU).
// Each wave owns one 16-col N-tile of the 256 gate rows; weight B-frags
// (bf16 hi+lo, ih+hh) live in 32 VGPRs (R6: 40 VGPR total, no spill).
// R7 change: the x-side GEMM for step t+1 is independent of h(t), so it moves
// into Phase B's window (w2): cell VALU (waves 0-7) || x-side MFMAs (all
// waves) || x(t+2) plane staging (waves 8-15). h-side (w1) is 2 independent
// 3-deep MFMA chains instead of one 12-deep chain. x planes double-buffered.
// Precision: 3-term bf16 split (whi*hhi + whi*hlo + wlo*hhi), fp32 accum.

#define T_STEPS 512
#define BATCH   2048
#define HID     64
#define NG      256
#define CB      8
#define NTHR    1024

typedef __attribute__((ext_vector_type(8))) short bf16x8;
typedef __attribute__((ext_vector_type(4))) float f32x4;

__device__ __forceinline__ float sigm(float z) { return 1.0f / (1.0f + __expf(-z)); }
__device__ __forceinline__ float tanh_f(float z) {
    z = fminf(15.0f, fmaxf(-15.0f, z));
    const float e = __expf(2.0f * z);
    return (e - 1.0f) / (e + 1.0f);
}
// truncate f32 -> bf16 (lo term captures the remainder)
__device__ __forceinline__ short tb(float v) { return (short)(__float_as_uint(v) >> 16); }
__device__ __forceinline__ float fb(short h) {
    return __uint_as_float(((unsigned)(unsigned short)h) << 16);
}
// XOR-swizzled byte address of 16B unit u8 (0..7) in an [8][64]-bf16 plane
__device__ __forceinline__ int paddr(int row, int u8) {
    row &= 7;
    return row * 128 + ((u8 ^ row) << 4);
}
__device__ __forceinline__ void pwr(short* plane, int row, int k, short v) {
    *(short*)((char*)plane + paddr(row, k >> 3) + (k & 7) * 2) = v;
}
__device__ __forceinline__ bf16x8 prd(const short* plane, int row, int u8) {
    return *(const bf16x8*)((const char*)plane + paddr(row, u8));
}

// x-side accumulation for one timestep from x-plane buffer nb into Cx
#define CX_STEP(nb) do {                                                     \
    _Pragma("unroll")                                                        \
    for (int s_ = 0; s_ < 2; ++s_) {                                         \
        if (s_ * 32 < Din) {                                                 \
            const bf16x8 axh = prd(&xhi[nb][0], arow, s_ * 4 + ksub);        \
            const bf16x8 axl = prd(&xlo[nb][0], arow, s_ * 4 + ksub);        \
            Cx = __builtin_amdgcn_mfma_f32_16x16x32_bf16(axh, BIh[s_], Cx, 0, 0, 0); \
            Cx = __builtin_amdgcn_mfma_f32_16x16x32_bf16(axl, BIh[s_], Cx, 0, 0, 0); \
            Cx = __builtin_amdgcn_mfma_f32_16x16x32_bf16(axh, BIl[s_], Cx, 0, 0, 0); \
        }                                                                    \
    }                                                                        \
} while (0)

__global__ __launch_bounds__(NTHR) void lstm_layer(
    const float* __restrict__ x0,    // layer0 input [B][T][16] fp32, or null
    unsigned*    __restrict__ hseq,  // [T][B][64] packed bf16 hi|lo<<16
    const float* __restrict__ Wih,   // [256][Din]
    const float* __restrict__ Whh,   // [256][64]
    const float* __restrict__ bih,   // [256]
    const float* __restrict__ bhh,   // [256]
    const float* __restrict__ Wout,  // [7][64] (head only)
    const float* __restrict__ bout,  // [7]
    float* __restrict__ out,         // [B][7]
    int Din, int store_h, int do_head)
{
    __shared__ __attribute__((aligned(16))) short xhi[2][8 * 64], xlo[2][8 * 64];
    __shared__ __attribute__((aligned(16))) short hhi[8 * 64], hlo[8 * 64];
    __shared__ __attribute__((aligned(16))) float gts[8 * NG];
    __shared__ __attribute__((aligned(16))) float hf[8 * HID];

    const int tid  = threadIdx.x;
    const int lane = tid & 63;
    const int wid  = tid >> 6;          // 0..15: N-tile index
    const int ncol = wid * 16 + (lane & 15);
    const int ksub = (lane >> 4) & 3;   // k-subgroup of 8
    const int arow = lane & 15;
    const int b0   = blockIdx.x * CB;

    // ---- weight B-fragments, resident in registers for the whole kernel ----
    bf16x8 BIh[2], BIl[2], BHh[2], BHl[2];
    #pragma unroll
    for (int s = 0; s < 2; ++s) {
        bf16x8 h8 = {0, 0, 0, 0, 0, 0, 0, 0};
        bf16x8 l8 = {0, 0, 0, 0, 0, 0, 0, 0};
        const int k0 = s * 32 + ksub * 8;
        if (k0 < Din) {
            const float4 a = *(const float4*)(Wih + ncol * Din + k0);
            const float4 b = *(const float4*)(Wih + ncol * Din + k0 + 4);
            const float v[8] = {a.x, a.y, a.z, a.w, b.x, b.y, b.z, b.w};
            #pragma unroll
            for (int e = 0; e < 8; ++e) {
                h8[e] = tb(v[e]);
                l8[e] = tb(v[e] - fb(h8[e]));
            }
        }
        BIh[s] = h8; BIl[s] = l8;
    }
    #pragma unroll
    for (int s = 0; s < 2; ++s) {
        bf16x8 h8, l8;
        const int k0 = s * 32 + ksub * 8;
        const float4 a = *(const float4*)(Whh + ncol * HID + k0);
        const float4 b = *(const float4*)(Whh + ncol * HID + k0 + 4);
        const float v[8] = {a.x, a.y, a.z, a.w, b.x, b.y, b.z, b.w};
        #pragma unroll
        for (int e = 0; e < 8; ++e) {
            h8[e] = tb(v[e]);
            l8[e] = tb(v[e] - fb(h8[e]));
        }
        BHh[s] = h8; BHl[s] = l8;
    }
    const float biasr = bih[ncol] + bhh[ncol];

    // ---- zero h planes and both x buffers ----
    {
        hhi[tid & 511] = 0; hlo[tid & 511] = 0;   // 1024 threads, 512 slots: 2x
        ((short*)xhi)[tid] = 0; ((short*)xlo)[tid] = 0;
    }
    __syncthreads();   // (zeroing races with itself harmlessly: all zeros)

    // ---- stage input tiles t=0 (buf0) and t=1 (buf1): waves 8-15 ----
    if (tid >= 512) {
        const int t2 = tid - 512;
        if (x0) {
            if (t2 < 128) {
                const int b = t2 >> 4, k = t2 & 15;
                #pragma unroll
                for (int tt = 0; tt < 2; ++tt) {
                    const float v = x0[(size_t)(b0 + b) * (T_STEPS * 16) + tt * 16 + k];
                    const short hh_ = tb(v);
                    pwr(&xhi[tt][0], b, k, hh_);
                    pwr(&xlo[tt][0], b, k, tb(v - fb(hh_)));
                }
            }
        } else {
            const int b = t2 >> 6, u = t2 & 63;
            #pragma unroll
            for (int tt = 0; tt < 2; ++tt) {
                const unsigned p = hseq[(size_t)tt * BATCH * HID + (b0 + b) * HID + u];
                pwr(&xhi[tt][0], b, u, (short)(p & 0xffff));
                pwr(&xlo[tt][0], b, u, (short)(p >> 16));
            }
        }
    }
    __syncthreads();

    // ---- prologue: Cx for t=0 from buffer 0 ----
    f32x4 Cx = {0.f, 0.f, 0.f, 0.f};
    CX_STEP(0);

    float cst = 0.0f;   // c state (threads < 512: one (b,u) cell each)

    for (int t = 0; t < T_STEPS; ++t) {
        // ---- w1: issue x(t+2) prefetch; h-side MFMA (2 chains of 3) ----
        float pxn = 0.0f; unsigned phn = 0;
        if (tid >= 512 && t + 2 < T_STEPS) {
            const int t2 = tid - 512;
            if (x0) {
                if (t2 < 128)
                    pxn = x0[(size_t)(b0 + (t2 >> 4)) * (T_STEPS * 16) + (t + 2) * 16 + (t2 & 15)];
            } else {
                phn = hseq[(size_t)(t + 2) * BATCH * HID + (b0 + (t2 >> 6)) * HID + (t2 & 63)];
            }
        }

        f32x4 Ch0 = {0.f, 0.f, 0.f, 0.f};
        f32x4 Ch1 = {0.f, 0.f, 0.f, 0.f};
        {
            const bf16x8 ah0 = prd(hhi, arow, 0 + ksub);
            const bf16x8 al0 = prd(hlo, arow, 0 + ksub);
            const bf16x8 ah1 = prd(hhi, arow, 4 + ksub);
            const bf16x8 al1 = prd(hlo, arow, 4 + ksub);
            Ch0 = __builtin_amdgcn_mfma_f32_16x16x32_bf16(ah0, BHh[0], Ch0, 0, 0, 0);
            Ch1 = __builtin_amdgcn_mfma_f32_16x16x32_bf16(ah1, BHh[1], Ch1, 0, 0, 0);
            Ch0 = __builtin_amdgcn_mfma_f32_16x16x32_bf16(al0, BHh[0], Ch0, 0, 0, 0);
            Ch1 = __builtin_amdgcn_mfma_f32_16x16x32_bf16(al1, BHh[1], Ch1, 0, 0, 0);
            Ch0 = __builtin_amdgcn_mfma_f32_16x16x32_bf16(ah0, BHl[0], Ch0, 0, 0, 0);
            Ch1 = __builtin_amdgcn_mfma_f32_16x16x32_bf16(ah1, BHl[1], Ch1, 0, 0, 0);
        }
        #pragma unroll
        for (int j = 0; j < 4; ++j) {
            const int r2 = (lane >> 4) * 4 + j;
            if (r2 < 8) gts[r2 * NG + ncol] = Cx[j] + Ch0[j] + Ch1[j] + biasr;
        }
        __syncthreads();

        // ---- w2: x-side MFMA for t+1 || cell math || x(t+2) staging ----
        Cx[0] = 0.f; Cx[1] = 0.f; Cx[2] = 0.f; Cx[3] = 0.f;
        const int nb = (t + 1) & 1;
        CX_STEP(nb);

        if (tid < 512) {
            const int b = tid >> 6, u = tid & 63;
            const float gi = gts[b * NG + u];
            const float gf = gts[b * NG + 64 + u];
            const float gg = gts[b * NG + 128 + u];
            const float go = gts[b * NG + 192 + u];
            cst = sigm(gf) * cst + sigm(gi) * tanh_f(gg);
            const float h = sigm(go) * tanh_f(cst);
            const short h_hi = tb(h);
            const short h_lo = tb(h - fb(h_hi));
            pwr(hhi, b, u, h_hi);
            pwr(hlo, b, u, h_lo);
            if (store_h)
                hseq[(size_t)t * BATCH * HID + (b0 + b) * HID + u] =
                    (unsigned)(unsigned short)h_hi | ((unsigned)(unsigned short)h_lo << 16);
            if (do_head && t == T_STEPS - 1) hf[b * HID + u] = h;
        } else if (t + 2 < T_STEPS) {
            const int t2 = tid - 512;
            const int wb = t & 1;   // (t+2)&1 == t&1
            if (x0) {
                if (t2 < 128) {
                    const int b = t2 >> 4, k = t2 & 15;
                    const short hh_ = tb(pxn);
                    pwr(&xhi[wb][0], b, k, hh_);
                    pwr(&xlo[wb][0], b, k, tb(pxn - fb(hh_)));
                }
            } else {
                const int b = t2 >> 6, u = t2 & 63;
                pwr(&xhi[wb][0], b, u, (short)(phn & 0xffff));
                pwr(&xlo[wb][0], b, u, (short)(phn >> 16));
            }
        }
        __syncthreads();
    }

    // ---- head: out = h2[T-1] @ Wout^T + bout ----
    if (do_head && tid < 7 * CB) {
        const int b = tid / 7, o = tid % 7;
        float a = bout[o];
        #pragma unroll
        for (int k = 0; k < HID; ++k)
            a = fmaf(hf[b * HID + k], Wout[o * HID + k], a);
        out[(b0 + b) * 7 + o] = a;
    }
}

extern "C" void kernel_launch(void* const* d_in, const int* in_sizes, int n_in,
                              void* d_out, int out_size, void* d_ws, size_t ws_size,
                              hipStream_t stream) {
    const float* x    = (const float*)d_in[0];
    const float* Wih0 = (const float*)d_in[1];
    const float* Whh0 = (const float*)d_in[2];
    const float* bih0 = (const float*)d_in[3];
    const float* bhh0 = (const float*)d_in[4];
    const float* Wih1 = (const float*)d_in[5];
    const float* Whh1 = (const float*)d_in[6];
    const float* bih1 = (const float*)d_in[7];
    const float* bhh1 = (const float*)d_in[8];
    const float* Wih2 = (const float*)d_in[9];
    const float* Whh2 = (const float*)d_in[10];
    const float* bih2 = (const float*)d_in[11];
    const float* bhh2 = (const float*)d_in[12];
    const float* Wout = (const float*)d_in[13];
    const float* bout = (const float*)d_in[14];
    float* out = (float*)d_out;
    unsigned* hseq = (unsigned*)d_ws;   // needs T*B*64*4 = 268,435,456 B

    const dim3 grid(BATCH / CB), blk(NTHR);
    lstm_layer<<<grid, blk, 0, stream>>>(x, hseq, Wih0, Whh0, bih0, bhh0,
                                         nullptr, nullptr, nullptr, 16, 1, 0);
    lstm_layer<<<grid, blk, 0, stream>>>(nullptr, hseq, Wih1, Whh1, bih1, bhh1,
                                         nullptr, nullptr, nullptr, HID, 1, 0);
    lstm_layer<<<grid, blk, 0, stream>>>(nullptr, hseq, Wih2, Whh2, bih2, bhh2,
                                         Wout, bout, out, HID, 0, 1);
}

// Round 8
// 1487.133 us; speedup vs baseline: 4.5019x; 1.0292x over previous
//
#include <hip/hip_runtime.h>
#include <math.h>

// 3-layer LSTM (H=64, T=512, B=2048, Din=16), R8: layer-sequential MFMA,
// software-pipelined + two-timestep x-side batching.
// 3 stream-ordered dispatches (head fused into layer 2). Per block: 1024
// threads = 16 waves, CB=8 batch rows, grid 256 (1 block/CU). Each wave owns
// one 16-col N-tile of the 256 gate rows; weight B-frags (bf16 hi+lo, ih+hh)
// live in 32 VGPRs.
// R8 change: the MFMA A-tile has 16 rows but CB=8 -> rows 8-15 were wasted.
// x-side now packs step t+1 in rows 0-7 and t+2 in rows 8-15 and runs every
// OTHER iteration (x planes are [2][16][64], double-buffered pairs); the
// gts writeout selects the lane-half matching t's parity. The h-side plane
// read aliases rows 8-15 to 0-7 (broadcast), so its C rows 8-15 are valid
// duplicates. Halves x-side LDS reads + MFMA issue (we are LDS-issue-bound:
// 128 ds_read_b128/CU/iter ~= 1536 of 2880 cyc measured in R7).
// Precision: 3-term bf16 split (whi*hhi + whi*hlo + wlo*hhi), fp32 accum.

#define T_STEPS 512
#define BATCH   2048
#define HID     64
#define NG      256
#define CB      8
#define NTHR    1024
#define SEQS    (BATCH * HID)     // hseq elements per timestep

typedef __attribute__((ext_vector_type(8))) short bf16x8;
typedef __attribute__((ext_vector_type(4))) float f32x4;

__device__ __forceinline__ float sigm(float z) { return 1.0f / (1.0f + __expf(-z)); }
__device__ __forceinline__ float tanh_f(float z) {
    z = fminf(15.0f, fmaxf(-15.0f, z));
    const float e = __expf(2.0f * z);
    return (e - 1.0f) / (e + 1.0f);
}
// truncate f32 -> bf16 (lo term captures the remainder)
__device__ __forceinline__ short tb(float v) { return (short)(__float_as_uint(v) >> 16); }
__device__ __forceinline__ float fb(short h) {
    return __uint_as_float(((unsigned)(unsigned short)h) << 16);
}
// 8-row plane (h): row aliases &7 -> A rows 8-15 broadcast rows 0-7 (free dup)
__device__ __forceinline__ int ha(int row, int u8) {
    row &= 7;
    return row * 128 + ((u8 ^ row) << 4);
}
// 16-row plane (x): real 16 rows (t+1 in 0-7, t+2 in 8-15), XOR on row&7
__device__ __forceinline__ int xaddr(int row, int u8) {
    return row * 128 + ((u8 ^ (row & 7)) << 4);
}
__device__ __forceinline__ void hwr(short* p, int row, int k, short v) {
    *(short*)((char*)p + ha(row, k >> 3) + (k & 7) * 2) = v;
}
__device__ __forceinline__ bf16x8 hrd(const short* p, int row, int u8) {
    return *(const bf16x8*)((const char*)p + ha(row, u8));
}
__device__ __forceinline__ void xwr(short* p, int row, int k, short v) {
    *(short*)((char*)p + xaddr(row, k >> 3) + (k & 7) * 2) = v;
}
__device__ __forceinline__ bf16x8 xrd(const short* p, int row, int u8) {
    return *(const bf16x8*)((const char*)p + xaddr(row, u8));
}

// x-side pass over plane buffer NB -> DST (covers 2 timesteps: rows 0-7, 8-15)
#define X_PASS(DST, NB) do {                                                  \
    DST[0] = 0.f; DST[1] = 0.f; DST[2] = 0.f; DST[3] = 0.f;                   \
    _Pragma("unroll")                                                         \
    for (int s_ = 0; s_ < 2; ++s_) {                                          \
        if (s_ * 32 < Din) {                                                  \
            const bf16x8 axh = xrd(&xhi[NB][0], arow, s_ * 4 + ksub);         \
            const bf16x8 axl = xrd(&xlo[NB][0], arow, s_ * 4 + ksub);         \
            DST = __builtin_amdgcn_mfma_f32_16x16x32_bf16(axh, BIh[s_], DST, 0, 0, 0); \
            DST = __builtin_amdgcn_mfma_f32_16x16x32_bf16(axl, BIh[s_], DST, 0, 0, 0); \
            DST = __builtin_amdgcn_mfma_f32_16x16x32_bf16(axh, BIl[s_], DST, 0, 0, 0); \
        }                                                                     \
    }                                                                         \
} while (0)

__global__ __launch_bounds__(NTHR) void lstm_layer(
    const float* __restrict__ x0,    // layer0 input [B][T][16] fp32, or null
    unsigned*    __restrict__ hseq,  // [T][B][64] packed bf16 hi|lo<<16
    const float* __restrict__ Wih,   // [256][Din]
    const float* __restrict__ Whh,   // [256][64]
    const float* __restrict__ bih,   // [256]
    const float* __restrict__ bhh,   // [256]
    const float* __restrict__ Wout,  // [7][64] (head only)
    const float* __restrict__ bout,  // [7]
    float* __restrict__ out,         // [B][7]
    int Din, int store_h, int do_head)
{
    __shared__ __attribute__((aligned(16))) short xhi[2][16 * 64], xlo[2][16 * 64];
    __shared__ __attribute__((aligned(16))) short hhi[8 * 64], hlo[8 * 64];
    __shared__ __attribute__((aligned(16))) float gts[8 * NG];
    __shared__ __attribute__((aligned(16))) float hf[8 * HID];

    const int tid  = threadIdx.x;
    const int lane = tid & 63;
    const int wid  = tid >> 6;          // 0..15: N-tile index
    const int ncol = wid * 16 + (lane & 15);
    const int ksub = (lane >> 4) & 3;   // k-subgroup of 8
    const int arow = lane & 15;
    const int b0   = blockIdx.x * CB;

    // ---- weight B-fragments, resident in registers for the whole kernel ----
    bf16x8 BIh[2], BIl[2], BHh[2], BHl[2];
    #pragma unroll
    for (int s = 0; s < 2; ++s) {
        bf16x8 h8 = {0, 0, 0, 0, 0, 0, 0, 0};
        bf16x8 l8 = {0, 0, 0, 0, 0, 0, 0, 0};
        const int k0 = s * 32 + ksub * 8;
        if (k0 < Din) {
            const float4 a = *(const float4*)(Wih + ncol * Din + k0);
            const float4 b = *(const float4*)(Wih + ncol * Din + k0 + 4);
            const float v[8] = {a.x, a.y, a.z, a.w, b.x, b.y, b.z, b.w};
            #pragma unroll
            for (int e = 0; e < 8; ++e) {
                h8[e] = tb(v[e]);
                l8[e] = tb(v[e] - fb(h8[e]));
            }
        }
        BIh[s] = h8; BIl[s] = l8;
    }
    #pragma unroll
    for (int s = 0; s < 2; ++s) {
        bf16x8 h8, l8;
        const int k0 = s * 32 + ksub * 8;
        const float4 a = *(const float4*)(Whh + ncol * HID + k0);
        const float4 b = *(const float4*)(Whh + ncol * HID + k0 + 4);
        const float v[8] = {a.x, a.y, a.z, a.w, b.x, b.y, b.z, b.w};
        #pragma unroll
        for (int e = 0; e < 8; ++e) {
            h8[e] = tb(v[e]);
            l8[e] = tb(v[e] - fb(h8[e]));
        }
        BHh[s] = h8; BHl[s] = l8;
    }
    const float biasr = bih[ncol] + bhh[ncol];

    // ---- zero h planes and both x buffers ----
    hhi[tid & 511] = 0; hlo[tid & 511] = 0;
    ((short*)xhi)[tid] = 0; ((short*)xhi)[tid + 1024] = 0;
    ((short*)xlo)[tid] = 0; ((short*)xlo)[tid + 1024] = 0;
    __syncthreads();

    // ---- prologue: stage steps 0..3 (pairs {0,1}->buf0, {2,3}->buf1) ----
    if (tid >= 512) {
        const int t2 = tid - 512;
        if (x0) {
            if (t2 < 128) {
                const int b = t2 >> 4, k = t2 & 15;
                #pragma unroll
                for (int s = 0; s < 4; ++s) {
                    const float v = x0[(size_t)(b0 + b) * (T_STEPS * 16) + s * 16 + k];
                    const short hh_ = tb(v);
                    const int row = ((s & 1) << 3) + b;
                    xwr(&xhi[(s >> 1) & 1][0], row, k, hh_);
                    xwr(&xlo[(s >> 1) & 1][0], row, k, tb(v - fb(hh_)));
                }
            }
        } else {
            const int b = t2 >> 6, u = t2 & 63;
            #pragma unroll
            for (int s = 0; s < 4; ++s) {
                const unsigned p = hseq[(size_t)s * SEQS + (b0 + b) * HID + u];
                const int row = ((s & 1) << 3) + b;
                xwr(&xhi[(s >> 1) & 1][0], row, u, (short)(p & 0xffff));
                xwr(&xlo[(s >> 1) & 1][0], row, u, (short)(p >> 16));
            }
        }
    }
    __syncthreads();

    // ---- prologue: x contribution for pair {0,1} ----
    f32x4 CxCur; X_PASS(CxCur, 0);
    f32x4 CxNext = {0.f, 0.f, 0.f, 0.f};

    float cst = 0.0f;   // c state (threads < 512: one (b,u) cell each)

    // running pointers (hoisted addressing)
    const unsigned* hin = hseq + (size_t)4 * SEQS +
                          (size_t)(b0 + ((tid - 512) >> 6)) * HID + ((tid - 512) & 63);
    const float* xin = x0 ? x0 + (size_t)(b0 + ((tid - 512) >> 4)) * (T_STEPS * 16) +
                             4 * 16 + ((tid - 512) & 15)
                          : nullptr;
    unsigned* hout = hseq + (size_t)(b0 + (tid >> 6)) * HID + (tid & 63);

    for (int t = 0; t < T_STEPS; ++t) {
        // ---- w1: issue x(t+4) prefetch; h-side MFMA (2 chains of 3) ----
        float pxn = 0.0f; unsigned phn = 0;
        if (tid >= 512 && t + 4 < T_STEPS) {
            if (x0) {
                if (tid - 512 < 128) pxn = *xin;
            } else {
                phn = *hin;
            }
        }

        f32x4 Ch0 = {0.f, 0.f, 0.f, 0.f};
        f32x4 Ch1 = {0.f, 0.f, 0.f, 0.f};
        {
            const bf16x8 ah0 = hrd(hhi, arow, 0 + ksub);
            const bf16x8 al0 = hrd(hlo, arow, 0 + ksub);
            const bf16x8 ah1 = hrd(hhi, arow, 4 + ksub);
            const bf16x8 al1 = hrd(hlo, arow, 4 + ksub);
            Ch0 = __builtin_amdgcn_mfma_f32_16x16x32_bf16(ah0, BHh[0], Ch0, 0, 0, 0);
            Ch1 = __builtin_amdgcn_mfma_f32_16x16x32_bf16(ah1, BHh[1], Ch1, 0, 0, 0);
            Ch0 = __builtin_amdgcn_mfma_f32_16x16x32_bf16(al0, BHh[0], Ch0, 0, 0, 0);
            Ch1 = __builtin_amdgcn_mfma_f32_16x16x32_bf16(al1, BHh[1], Ch1, 0, 0, 0);
            Ch0 = __builtin_amdgcn_mfma_f32_16x16x32_bf16(ah0, BHl[0], Ch0, 0, 0, 0);
            Ch1 = __builtin_amdgcn_mfma_f32_16x16x32_bf16(ah1, BHl[1], Ch1, 0, 0, 0);
        }
        // gts writeout: pick the lane-half matching t's parity
        {
            const int rsh = (t & 1) << 3;
            #pragma unroll
            for (int j = 0; j < 4; ++j) {
                const int row = (lane >> 4) * 4 + j - rsh;
                if ((unsigned)row < 8u)
                    gts[row * NG + ncol] = CxCur[j] + Ch0[j] + Ch1[j] + biasr;
            }
        }
        __syncthreads();

        // ---- w2: (even t) x-pass for pair {t+2,t+3} || cell || staging ----
        if ((t & 1) == 0 && t + 2 < T_STEPS) {
            X_PASS(CxNext, ((t >> 1) + 1) & 1);
        }

        if (tid < 512) {
            const int b = tid >> 6, u = tid & 63;
            const float gi = gts[b * NG + u];
            const float gf = gts[b * NG + 64 + u];
            const float gg = gts[b * NG + 128 + u];
            const float go = gts[b * NG + 192 + u];
            cst = sigm(gf) * cst + sigm(gi) * tanh_f(gg);
            const float h = sigm(go) * tanh_f(cst);
            const short h_hi = tb(h);
            const short h_lo = tb(h - fb(h_hi));
            hwr(hhi, b, u, h_hi);
            hwr(hlo, b, u, h_lo);
            if (store_h)
                *hout = (unsigned)(unsigned short)h_hi |
                        ((unsigned)(unsigned short)h_lo << 16);
            if (do_head && t == T_STEPS - 1) hf[b * HID + u] = h;
        } else if (t + 4 < T_STEPS) {
            const int t2 = tid - 512;
            const int wb = (t >> 1) & 1;            // buffer of pair (t+4)>>1
            const int rsh = (t & 1) << 3;           // row half of step t+4
            if (x0) {
                if (t2 < 128) {
                    const int b = t2 >> 4, k = t2 & 15;
                    const short hh_ = tb(pxn);
                    xwr(&xhi[wb][0], rsh + b, k, hh_);
                    xwr(&xlo[wb][0], rsh + b, k, tb(pxn - fb(hh_)));
                }
            } else {
                const int b = t2 >> 6, u = t2 & 63;
                xwr(&xhi[wb][0], rsh + b, u, (short)(phn & 0xffff));
                xwr(&xlo[wb][0], rsh + b, u, (short)(phn >> 16));
            }
        }
        __syncthreads();

        if (t & 1) CxCur = CxNext;   // pair hand-off (wave-uniform branch)
        hin += SEQS;
        if (x0) xin += 16;
        hout += SEQS;
    }

    // ---- head: out = h2[T-1] @ Wout^T + bout ----
    if (do_head && tid < 7 * CB) {
        const int b = tid / 7, o = tid % 7;
        float a = bout[o];
        #pragma unroll
        for (int k = 0; k < HID; ++k)
            a = fmaf(hf[b * HID + k], Wout[o * HID + k], a);
        out[(b0 + b) * 7 + o] = a;
    }
}

extern "C" void kernel_launch(void* const* d_in, const int* in_sizes, int n_in,
                              void* d_out, int out_size, void* d_ws, size_t ws_size,
                              hipStream_t stream) {
    const float* x    = (const float*)d_in[0];
    const float* Wih0 = (const float*)d_in[1];
    const float* Whh0 = (const float*)d_in[2];
    const float* bih0 = (const float*)d_in[3];
    const float* bhh0 = (const float*)d_in[4];
    const float* Wih1 = (const float*)d_in[5];
    const float* Whh1 = (const float*)d_in[6];
    const float* bih1 = (const float*)d_in[7];
    const float* bhh1 = (const float*)d_in[8];
    const float* Wih2 = (const float*)d_in[9];
    const float* Whh2 = (const float*)d_in[10];
    const float* bih2 = (const float*)d_in[11];
    const float* bhh2 = (const float*)d_in[12];
    const float* Wout = (const float*)d_in[13];
    const float* bout = (const float*)d_in[14];
    float* out = (float*)d_out;
    unsigned* hseq = (unsigned*)d_ws;   // needs T*B*64*4 = 268,435,456 B

    const dim3 grid(BATCH / CB), blk(NTHR);
    lstm_layer<<<grid, blk, 0, stream>>>(x, hseq, Wih0, Whh0, bih0, bhh0,
                                         nullptr, nullptr, nullptr, 16, 1, 0);
    lstm_layer<<<grid, blk, 0, stream>>>(nullptr, hseq, Wih1, Whh1, bih1, bhh1,
                                         nullptr, nullptr, nullptr, HID, 1, 0);
    lstm_layer<<<grid, blk, 0, stream>>>(nullptr, hseq, Wih2, Whh2, bih2, bhh2,
                                         Wout, bout, out, HID, 0, 1);
}

// Round 9
// 1416.586 us; speedup vs baseline: 4.7262x; 1.0498x over previous
//
#include <hip/hip_runtime.h>
#include <math.h>

// 3-layer LSTM (H=64, T=512, B=2048, Din=16), R9: layer-sequential MFMA,
// software-pipelined, two-timestep x batching, fp16 recurrent path.
// 3 stream-ordered dispatches (head fused into layer 2). Per block: 1024
// threads = 16 waves, CB=8 batch rows, grid 256 (1 block/CU). Each wave owns
// one 16-col N-tile of the 256 gate rows.
// R9 change: h plane is ONE fp16 plane (|h|<=1 -> fp16 safe, rel err 2^-11)
// instead of bf16 hi+lo pair; W_hh is a 2-term fp16 hi+lo split (w err
// negligible). Halves the dominant LDS term (h A-frag reads: 64 -> 32
// ds_read_b128/CU/iter, R8 accounting) and shortens the h MFMA chain 3 -> 2.
// x-path numerics unchanged (bf16 3-term, fp32 cell, hseq bf16 hi|lo packed).

#define T_STEPS 512
#define BATCH   2048
#define HID     64
#define NG      256
#define CB      8
#define NTHR    1024
#define SEQS    (BATCH * HID)     // hseq elements per timestep

typedef __attribute__((ext_vector_type(8))) short bf16x8;
typedef __attribute__((ext_vector_type(8))) _Float16 f16x8;
typedef __attribute__((ext_vector_type(4))) float f32x4;

__device__ __forceinline__ float sigm(float z) { return 1.0f / (1.0f + __expf(-z)); }
__device__ __forceinline__ float tanh_f(float z) {
    z = fminf(15.0f, fmaxf(-15.0f, z));
    const float e = __expf(2.0f * z);
    return (e - 1.0f) / (e + 1.0f);
}
// truncate f32 -> bf16 (lo term captures the remainder)
__device__ __forceinline__ short tb(float v) { return (short)(__float_as_uint(v) >> 16); }
__device__ __forceinline__ float fb(short h) {
    return __uint_as_float(((unsigned)(unsigned short)h) << 16);
}
// 8-row 128B/row plane, XOR-swizzled 16B units (u8 in 0..7)
__device__ __forceinline__ int ha(int row, int u8) {
    row &= 7;
    return row * 128 + ((u8 ^ row) << 4);
}
// fp16 h plane accessors
__device__ __forceinline__ void hwr16(_Float16* p, int row, int u, _Float16 v) {
    *(_Float16*)((char*)p + ha(row, u >> 3) + (u & 7) * 2) = v;
}
__device__ __forceinline__ f16x8 hrd16(const _Float16* p, int row, int u8) {
    return *(const f16x8*)((const char*)p + ha(row, u8));
}
// 16-row bf16 x plane (t+1 in rows 0-7, t+2 in rows 8-15), XOR on row&7
__device__ __forceinline__ int xaddr(int row, int u8) {
    return row * 128 + ((u8 ^ (row & 7)) << 4);
}
__device__ __forceinline__ void xwr(short* p, int row, int k, short v) {
    *(short*)((char*)p + xaddr(row, k >> 3) + (k & 7) * 2) = v;
}
__device__ __forceinline__ bf16x8 xrd(const short* p, int row, int u8) {
    return *(const bf16x8*)((const char*)p + xaddr(row, u8));
}

// x-side pass over plane buffer NB -> DST (covers 2 timesteps: rows 0-7, 8-15)
#define X_PASS(DST, NB) do {                                                  \
    DST[0] = 0.f; DST[1] = 0.f; DST[2] = 0.f; DST[3] = 0.f;                   \
    _Pragma("unroll")                                                         \
    for (int s_ = 0; s_ < 2; ++s_) {                                          \
        if (s_ * 32 < Din) {                                                  \
            const bf16x8 axh = xrd(&xhi[NB][0], arow, s_ * 4 + ksub);         \
            const bf16x8 axl = xrd(&xlo[NB][0], arow, s_ * 4 + ksub);         \
            DST = __builtin_amdgcn_mfma_f32_16x16x32_bf16(axh, BIh[s_], DST, 0, 0, 0); \
            DST = __builtin_amdgcn_mfma_f32_16x16x32_bf16(axl, BIh[s_], DST, 0, 0, 0); \
            DST = __builtin_amdgcn_mfma_f32_16x16x32_bf16(axh, BIl[s_], DST, 0, 0, 0); \
        }                                                                     \
    }                                                                         \
} while (0)

__global__ __launch_bounds__(NTHR) void lstm_layer(
    const float* __restrict__ x0,    // layer0 input [B][T][16] fp32, or null
    unsigned*    __restrict__ hseq,  // [T][B][64] packed bf16 hi|lo<<16
    const float* __restrict__ Wih,   // [256][Din]
    const float* __restrict__ Whh,   // [256][64]
    const float* __restrict__ bih,   // [256]
    const float* __restrict__ bhh,   // [256]
    const float* __restrict__ Wout,  // [7][64] (head only)
    const float* __restrict__ bout,  // [7]
    float* __restrict__ out,         // [B][7]
    int Din, int store_h, int do_head)
{
    __shared__ __attribute__((aligned(16))) short xhi[2][16 * 64], xlo[2][16 * 64];
    __shared__ __attribute__((aligned(16))) _Float16 hpf[8 * 64];
    __shared__ __attribute__((aligned(16))) float gts[8 * NG];
    __shared__ __attribute__((aligned(16))) float hf[8 * HID];

    const int tid  = threadIdx.x;
    const int lane = tid & 63;
    const int wid  = tid >> 6;          // 0..15: N-tile index
    const int ncol = wid * 16 + (lane & 15);
    const int ksub = (lane >> 4) & 3;   // k-subgroup of 8
    const int arow = lane & 15;
    const int b0   = blockIdx.x * CB;

    // ---- weight fragments, resident in registers for the whole kernel ----
    bf16x8 BIh[2], BIl[2];     // x-side: bf16 hi+lo (numerics unchanged)
    f16x8  WHh[2], WHl[2];     // h-side: fp16 hi+lo 2-term
    #pragma unroll
    for (int s = 0; s < 2; ++s) {
        bf16x8 h8 = {0, 0, 0, 0, 0, 0, 0, 0};
        bf16x8 l8 = {0, 0, 0, 0, 0, 0, 0, 0};
        const int k0 = s * 32 + ksub * 8;
        if (k0 < Din) {
            const float4 a = *(const float4*)(Wih + ncol * Din + k0);
            const float4 b = *(const float4*)(Wih + ncol * Din + k0 + 4);
            const float v[8] = {a.x, a.y, a.z, a.w, b.x, b.y, b.z, b.w};
            #pragma unroll
            for (int e = 0; e < 8; ++e) {
                h8[e] = tb(v[e]);
                l8[e] = tb(v[e] - fb(h8[e]));
            }
        }
        BIh[s] = h8; BIl[s] = l8;
    }
    #pragma unroll
    for (int s = 0; s < 2; ++s) {
        f16x8 h8, l8;
        const int k0 = s * 32 + ksub * 8;
        const float4 a = *(const float4*)(Whh + ncol * HID + k0);
        const float4 b = *(const float4*)(Whh + ncol * HID + k0 + 4);
        const float v[8] = {a.x, a.y, a.z, a.w, b.x, b.y, b.z, b.w};
        #pragma unroll
        for (int e = 0; e < 8; ++e) {
            const _Float16 hi = (_Float16)v[e];
            h8[e] = hi;
            l8[e] = (_Float16)(v[e] - (float)hi);
        }
        WHh[s] = h8; WHl[s] = l8;
    }
    const float biasr = bih[ncol] + bhh[ncol];

    // ---- zero h plane and both x buffers ----
    hpf[tid & 511] = (_Float16)0.f;
    ((short*)xhi)[tid] = 0; ((short*)xhi)[tid + 1024] = 0;
    ((short*)xlo)[tid] = 0; ((short*)xlo)[tid + 1024] = 0;
    __syncthreads();

    // ---- prologue: stage steps 0..3 (pairs {0,1}->buf0, {2,3}->buf1) ----
    if (tid >= 512) {
        const int t2 = tid - 512;
        if (x0) {
            if (t2 < 128) {
                const int b = t2 >> 4, k = t2 & 15;
                #pragma unroll
                for (int s = 0; s < 4; ++s) {
                    const float v = x0[(size_t)(b0 + b) * (T_STEPS * 16) + s * 16 + k];
                    const short hh_ = tb(v);
                    const int row = ((s & 1) << 3) + b;
                    xwr(&xhi[(s >> 1) & 1][0], row, k, hh_);
                    xwr(&xlo[(s >> 1) & 1][0], row, k, tb(v - fb(hh_)));
                }
            }
        } else {
            const int b = t2 >> 6, u = t2 & 63;
            #pragma unroll
            for (int s = 0; s < 4; ++s) {
                const unsigned p = hseq[(size_t)s * SEQS + (b0 + b) * HID + u];
                const int row = ((s & 1) << 3) + b;
                xwr(&xhi[(s >> 1) & 1][0], row, u, (short)(p & 0xffff));
                xwr(&xlo[(s >> 1) & 1][0], row, u, (short)(p >> 16));
            }
        }
    }
    __syncthreads();

    // ---- prologue: x contribution for pair {0,1} ----
    f32x4 CxCur; X_PASS(CxCur, 0);
    f32x4 CxNext = {0.f, 0.f, 0.f, 0.f};

    float cst = 0.0f;   // c state (threads < 512: one (b,u) cell each)

    // running pointers (hoisted addressing)
    const unsigned* hin = hseq + (size_t)4 * SEQS +
                          (size_t)(b0 + ((tid - 512) >> 6)) * HID + ((tid - 512) & 63);
    const float* xin = x0 ? x0 + (size_t)(b0 + ((tid - 512) >> 4)) * (T_STEPS * 16) +
                             4 * 16 + ((tid - 512) & 15)
                          : nullptr;
    unsigned* hout = hseq + (size_t)(b0 + (tid >> 6)) * HID + (tid & 63);

    for (int t = 0; t < T_STEPS; ++t) {
        // ---- w1: issue x(t+4) prefetch; h-side MFMA (2 chains of 2) ----
        float pxn = 0.0f; unsigned phn = 0;
        if (tid >= 512 && t + 4 < T_STEPS) {
            if (x0) {
                if (tid - 512 < 128) pxn = *xin;
            } else {
                phn = *hin;
            }
        }

        f32x4 Ch0 = {0.f, 0.f, 0.f, 0.f};
        f32x4 Ch1 = {0.f, 0.f, 0.f, 0.f};
        {
            const f16x8 ah0 = hrd16(hpf, arow, ksub);       // k 0..31
            const f16x8 ah1 = hrd16(hpf, arow, 4 + ksub);   // k 32..63
            Ch0 = __builtin_amdgcn_mfma_f32_16x16x32_f16(ah0, WHh[0], Ch0, 0, 0, 0);
            Ch1 = __builtin_amdgcn_mfma_f32_16x16x32_f16(ah1, WHh[1], Ch1, 0, 0, 0);
            Ch0 = __builtin_amdgcn_mfma_f32_16x16x32_f16(ah0, WHl[0], Ch0, 0, 0, 0);
            Ch1 = __builtin_amdgcn_mfma_f32_16x16x32_f16(ah1, WHl[1], Ch1, 0, 0, 0);
        }
        // gts writeout: pick the lane-half matching t's parity
        {
            const int rsh = (t & 1) << 3;
            #pragma unroll
            for (int j = 0; j < 4; ++j) {
                const int row = (lane >> 4) * 4 + j - rsh;
                if ((unsigned)row < 8u)
                    gts[row * NG + ncol] = CxCur[j] + Ch0[j] + Ch1[j] + biasr;
            }
        }
        __syncthreads();

        // ---- w2: (even t) x-pass for pair {t+2,t+3} || cell || staging ----
        if ((t & 1) == 0 && t + 2 < T_STEPS) {
            X_PASS(CxNext, ((t >> 1) + 1) & 1);
        }

        if (tid < 512) {
            const int b = tid >> 6, u = tid & 63;
            const float gi = gts[b * NG + u];
            const float gf = gts[b * NG + 64 + u];
            const float gg = gts[b * NG + 128 + u];
            const float go = gts[b * NG + 192 + u];
            cst = sigm(gf) * cst + sigm(gi) * tanh_f(gg);
            const float h = sigm(go) * tanh_f(cst);
            hwr16(hpf, b, u, (_Float16)h);
            if (store_h) {
                const short h_hi = tb(h);
                const short h_lo = tb(h - fb(h_hi));
                *hout = (unsigned)(unsigned short)h_hi |
                        ((unsigned)(unsigned short)h_lo << 16);
            }
            if (do_head && t == T_STEPS - 1) hf[b * HID + u] = h;
        } else if (t + 4 < T_STEPS) {
            const int t2 = tid - 512;
            const int wb = (t >> 1) & 1;            // buffer of pair (t+4)>>1
            const int rsh = (t & 1) << 3;           // row half of step t+4
            if (x0) {
                if (t2 < 128) {
                    const int b = t2 >> 4, k = t2 & 15;
                    const short hh_ = tb(pxn);
                    xwr(&xhi[wb][0], rsh + b, k, hh_);
                    xwr(&xlo[wb][0], rsh + b, k, tb(pxn - fb(hh_)));
                }
            } else {
                const int b = t2 >> 6, u = t2 & 63;
                xwr(&xhi[wb][0], rsh + b, u, (short)(phn & 0xffff));
                xwr(&xlo[wb][0], rsh + b, u, (short)(phn >> 16));
            }
        }
        __syncthreads();

        if (t & 1) CxCur = CxNext;   // pair hand-off (wave-uniform branch)
        hin += SEQS;
        if (x0) xin += 16;
        hout += SEQS;
    }

    // ---- head: out = h2[T-1] @ Wout^T + bout ----
    if (do_head && tid < 7 * CB) {
        const int b = tid / 7, o = tid % 7;
        float a = bout[o];
        #pragma unroll
        for (int k = 0; k < HID; ++k)
            a = fmaf(hf[b * HID + k], Wout[o * HID + k], a);
        out[(b0 + b) * 7 + o] = a;
    }
}

extern "C" void kernel_launch(void* const* d_in, const int* in_sizes, int n_in,
                              void* d_out, int out_size, void* d_ws, size_t ws_size,
                              hipStream_t stream) {
    const float* x    = (const float*)d_in[0];
    const float* Wih0 = (const float*)d_in[1];
    const float* Whh0 = (const float*)d_in[2];
    const float* bih0 = (const float*)d_in[3];
    const float* bhh0 = (const float*)d_in[4];
    const float* Wih1 = (const float*)d_in[5];
    const float* Whh1 = (const float*)d_in[6];
    const float* bih1 = (const float*)d_in[7];
    const float* bhh1 = (const float*)d_in[8];
    const float* Wih2 = (const float*)d_in[9];
    const float* Whh2 = (const float*)d_in[10];
    const float* bih2 = (const float*)d_in[11];
    const float* bhh2 = (const float*)d_in[12];
    const float* Wout = (const float*)d_in[13];
    const float* bout = (const float*)d_in[14];
    float* out = (float*)d_out;
    unsigned* hseq = (unsigned*)d_ws;   // needs T*B*64*4 = 268,435,456 B

    const dim3 grid(BATCH / CB), blk(NTHR);
    lstm_layer<<<grid, blk, 0, stream>>>(x, hseq, Wih0, Whh0, bih0, bhh0,
                                         nullptr, nullptr, nullptr, 16, 1, 0);
    lstm_layer<<<grid, blk, 0, stream>>>(nullptr, hseq, Wih1, Whh1, bih1, bhh1,
                                         nullptr, nullptr, nullptr, HID, 1, 0);
    lstm_layer<<<grid, blk, 0, stream>>>(nullptr, hseq, Wih2, Whh2, bih2, bhh2,
                                         Wout, bout, out, HID, 0, 1);
}

// Round 11
// 1287.583 us; speedup vs baseline: 5.1997x; 1.1002x over previous
//
#include <hip/hip_runtime.h>
#include <math.h>

// 3-layer LSTM (H=64, T=512, B=2048, Din=16), R11.
// R10 (fp16 hseq + 256-thread staging) diverged post-timing: output depended
// on d_ws entry state; root cause not identified by inspection. R11 reverts to
// R9's PROVEN memory structure (u32 bf16 hi|lo hseq, 512-thread staging, bf16
// x planes, fp16 h plane) -- every LDS/global access byte-identical to R9 --
// and applies register-only compute cuts:
//  - W_hh 1-term fp16 (err 2^-12): h-side 2 MFMA folded onto the Cx
//    accumulator; deletes the Cx+Ch0+Ch1+bias merge adds.
//  - bias folded into X_PASS accumulator init.
//  - half-wave gts writeout guard.

#define T_STEPS 512
#define BATCH   2048
#define HID     64
#define NG      256
#define CB      8
#define NTHR    1024
#define SEQS    (BATCH * HID)     // hseq u32 elements per timestep

typedef __attribute__((ext_vector_type(8))) short bf16x8;
typedef __attribute__((ext_vector_type(8))) _Float16 f16x8;
typedef __attribute__((ext_vector_type(4))) float f32x4;

__device__ __forceinline__ float sigm(float z) { return 1.0f / (1.0f + __expf(-z)); }
__device__ __forceinline__ float tanh_f(float z) {
    z = fminf(15.0f, fmaxf(-15.0f, z));
    const float e = __expf(2.0f * z);
    return (e - 1.0f) / (e + 1.0f);
}
// truncate f32 -> bf16 (lo term captures the remainder)
__device__ __forceinline__ short tb(float v) { return (short)(__float_as_uint(v) >> 16); }
__device__ __forceinline__ float fb(short h) {
    return __uint_as_float(((unsigned)(unsigned short)h) << 16);
}
// 8-row 128B/row plane, XOR-swizzled 16B units (u8 in 0..7)
__device__ __forceinline__ int ha(int row, int u8) {
    row &= 7;
    return row * 128 + ((u8 ^ row) << 4);
}
// fp16 h plane accessors
__device__ __forceinline__ void hwr16(_Float16* p, int row, int u, _Float16 v) {
    *(_Float16*)((char*)p + ha(row, u >> 3) + (u & 7) * 2) = v;
}
__device__ __forceinline__ f16x8 hrd16(const _Float16* p, int row, int u8) {
    return *(const f16x8*)((const char*)p + ha(row, u8));
}
// 16-row bf16 x plane (t+1 in rows 0-7, t+2 in rows 8-15), XOR on row&7
__device__ __forceinline__ int xaddr(int row, int u8) {
    return row * 128 + ((u8 ^ (row & 7)) << 4);
}
__device__ __forceinline__ void xwr(short* p, int row, int k, short v) {
    *(short*)((char*)p + xaddr(row, k >> 3) + (k & 7) * 2) = v;
}
__device__ __forceinline__ bf16x8 xrd(const short* p, int row, int u8) {
    return *(const bf16x8*)((const char*)p + xaddr(row, u8));
}

#define MFMA16(A, B, C)  __builtin_amdgcn_mfma_f32_16x16x32_f16((A), (B), (C), 0, 0, 0)

// x-side pass over plane buffer NB -> DST (covers 2 timesteps; bias folded in)
#define X_PASS(DST, NB) do {                                                  \
    DST[0] = biasr; DST[1] = biasr; DST[2] = biasr; DST[3] = biasr;           \
    _Pragma("unroll")                                                         \
    for (int s_ = 0; s_ < 2; ++s_) {                                          \
        if (s_ * 32 < Din) {                                                  \
            const bf16x8 axh = xrd(&xhi[NB][0], arow, s_ * 4 + ksub);         \
            const bf16x8 axl = xrd(&xlo[NB][0], arow, s_ * 4 + ksub);         \
            DST = __builtin_amdgcn_mfma_f32_16x16x32_bf16(axh, BIh[s_], DST, 0, 0, 0); \
            DST = __builtin_amdgcn_mfma_f32_16x16x32_bf16(axl, BIh[s_], DST, 0, 0, 0); \
            DST = __builtin_amdgcn_mfma_f32_16x16x32_bf16(axh, BIl[s_], DST, 0, 0, 0); \
        }                                                                     \
    }                                                                         \
} while (0)

__global__ __launch_bounds__(NTHR) void lstm_layer(
    const float* __restrict__ x0,    // layer0 input [B][T][16] fp32, or null
    unsigned*    __restrict__ hseq,  // [T][B][64] packed bf16 hi|lo<<16
    const float* __restrict__ Wih,   // [256][Din]
    const float* __restrict__ Whh,   // [256][64]
    const float* __restrict__ bih,   // [256]
    const float* __restrict__ bhh,   // [256]
    const float* __restrict__ Wout,  // [7][64] (head only)
    const float* __restrict__ bout,  // [7]
    float* __restrict__ out,         // [B][7]
    int Din, int store_h, int do_head)
{
    __shared__ __attribute__((aligned(16))) short xhi[2][16 * 64], xlo[2][16 * 64];
    __shared__ __attribute__((aligned(16))) _Float16 hpf[8 * 64];
    __shared__ __attribute__((aligned(16))) float gts[8 * NG];
    __shared__ __attribute__((aligned(16))) float hf[8 * HID];

    const int tid  = threadIdx.x;
    const int lane = tid & 63;
    const int wid  = tid >> 6;          // 0..15: N-tile index
    const int ncol = wid * 16 + (lane & 15);
    const int ksub = (lane >> 4) & 3;   // k-subgroup of 8
    const int arow = lane & 15;
    const int b0   = blockIdx.x * CB;

    // ---- weight fragments, resident in registers for the whole kernel ----
    bf16x8 BIh[2], BIl[2];     // x-side: bf16 hi+lo (numerics unchanged)
    f16x8  WHh0, WHh1;         // h-side: fp16 1-term
    #pragma unroll
    for (int s = 0; s < 2; ++s) {
        bf16x8 h8 = {0, 0, 0, 0, 0, 0, 0, 0};
        bf16x8 l8 = {0, 0, 0, 0, 0, 0, 0, 0};
        const int k0 = s * 32 + ksub * 8;
        if (k0 < Din) {
            const float4 a = *(const float4*)(Wih + ncol * Din + k0);
            const float4 b = *(const float4*)(Wih + ncol * Din + k0 + 4);
            const float v[8] = {a.x, a.y, a.z, a.w, b.x, b.y, b.z, b.w};
            #pragma unroll
            for (int e = 0; e < 8; ++e) {
                h8[e] = tb(v[e]);
                l8[e] = tb(v[e] - fb(h8[e]));
            }
        }
        BIh[s] = h8; BIl[s] = l8;
    }
    {
        f16x8 w0, w1;
        const int k0 = ksub * 8;
        const float4 a = *(const float4*)(Whh + ncol * HID + k0);
        const float4 b = *(const float4*)(Whh + ncol * HID + k0 + 4);
        const float4 c = *(const float4*)(Whh + ncol * HID + 32 + k0);
        const float4 d = *(const float4*)(Whh + ncol * HID + 32 + k0 + 4);
        w0[0]=(_Float16)a.x; w0[1]=(_Float16)a.y; w0[2]=(_Float16)a.z; w0[3]=(_Float16)a.w;
        w0[4]=(_Float16)b.x; w0[5]=(_Float16)b.y; w0[6]=(_Float16)b.z; w0[7]=(_Float16)b.w;
        w1[0]=(_Float16)c.x; w1[1]=(_Float16)c.y; w1[2]=(_Float16)c.z; w1[3]=(_Float16)c.w;
        w1[4]=(_Float16)d.x; w1[5]=(_Float16)d.y; w1[6]=(_Float16)d.z; w1[7]=(_Float16)d.w;
        WHh0 = w0; WHh1 = w1;
    }
    const float biasr = bih[ncol] + bhh[ncol];

    // ---- zero h plane and both x buffers ----
    hpf[tid & 511] = (_Float16)0.f;
    ((short*)xhi)[tid] = 0; ((short*)xhi)[tid + 1024] = 0;
    ((short*)xlo)[tid] = 0; ((short*)xlo)[tid + 1024] = 0;
    __syncthreads();

    // ---- prologue: stage steps 0..3 (pairs {0,1}->buf0, {2,3}->buf1) ----
    if (tid >= 512) {
        const int t2 = tid - 512;
        if (x0) {
            if (t2 < 128) {
                const int b = t2 >> 4, k = t2 & 15;
                #pragma unroll
                for (int s = 0; s < 4; ++s) {
                    const float v = x0[(size_t)(b0 + b) * (T_STEPS * 16) + s * 16 + k];
                    const short hh_ = tb(v);
                    const int row = ((s & 1) << 3) + b;
                    xwr(&xhi[(s >> 1) & 1][0], row, k, hh_);
                    xwr(&xlo[(s >> 1) & 1][0], row, k, tb(v - fb(hh_)));
                }
            }
        } else {
            const int b = t2 >> 6, u = t2 & 63;
            #pragma unroll
            for (int s = 0; s < 4; ++s) {
                const unsigned p = hseq[(size_t)s * SEQS + (b0 + b) * HID + u];
                const int row = ((s & 1) << 3) + b;
                xwr(&xhi[(s >> 1) & 1][0], row, u, (short)(p & 0xffff));
                xwr(&xlo[(s >> 1) & 1][0], row, u, (short)(p >> 16));
            }
        }
    }
    __syncthreads();

    // ---- prologue: x contribution (+bias) for pair {0,1} ----
    f32x4 CxCur; X_PASS(CxCur, 0);
    f32x4 CxNext = {0.f, 0.f, 0.f, 0.f};

    float cst = 0.0f;   // c state (threads < 512: one (b,u) cell each)

    // running pointers (hoisted addressing)
    const unsigned* hin = hseq + (size_t)4 * SEQS +
                          (size_t)(b0 + ((tid - 512) >> 6)) * HID + ((tid - 512) & 63);
    const float* xin = x0 ? x0 + (size_t)(b0 + ((tid - 512) >> 4)) * (T_STEPS * 16) +
                             4 * 16 + ((tid - 512) & 15)
                          : nullptr;
    unsigned* hout = hseq + (size_t)(b0 + (tid >> 6)) * HID + (tid & 63);

    for (int t = 0; t < T_STEPS; ++t) {
        // ---- w1: issue x(t+4) prefetch; h-side MFMA folded onto Cx ----
        float pxn = 0.0f; unsigned phn = 0;
        if (tid >= 512 && t + 4 < T_STEPS) {
            if (x0) {
                if (tid - 512 < 128) pxn = *xin;
            } else {
                phn = *hin;
            }
        }

        f32x4 G;
        {
            const f16x8 ah0 = hrd16(hpf, arow, ksub);       // k 0..31
            const f16x8 ah1 = hrd16(hpf, arow, 4 + ksub);   // k 32..63
            G = MFMA16(ah0, WHh0, CxCur);
            G = MFMA16(ah1, WHh1, G);
        }
        // gts writeout: active half-wave by parity, stride-1024B stores
        if ((lane >> 5) == (t & 1)) {
            float* gd = &gts[(((lane >> 4) & 1) * 4) * NG + ncol];
            gd[0]      = G[0];
            gd[NG]     = G[1];
            gd[2 * NG] = G[2];
            gd[3 * NG] = G[3];
        }
        __syncthreads();

        // ---- w2: (even t) x-pass for pair {t+2,t+3} || cell || staging ----
        if ((t & 1) == 0 && t + 2 < T_STEPS) {
            X_PASS(CxNext, ((t >> 1) + 1) & 1);
        }

        if (tid < 512) {
            const int b = tid >> 6, u = tid & 63;
            const float* gsrc = &gts[b * NG + u];
            const float gi = gsrc[0];
            const float gf = gsrc[64];
            const float gg = gsrc[128];
            const float go = gsrc[192];
            cst = sigm(gf) * cst + sigm(gi) * tanh_f(gg);
            const float h = sigm(go) * tanh_f(cst);
            hwr16(hpf, b, u, (_Float16)h);
            if (store_h) {
                const short h_hi = tb(h);
                const short h_lo = tb(h - fb(h_hi));
                *hout = (unsigned)(unsigned short)h_hi |
                        ((unsigned)(unsigned short)h_lo << 16);
            }
            if (do_head && t == T_STEPS - 1) hf[b * HID + u] = h;
        } else if (t + 4 < T_STEPS) {
            const int t2 = tid - 512;
            const int wb = (t >> 1) & 1;            // buffer of pair (t+4)>>1
            const int rsh = (t & 1) << 3;           // row half of step t+4
            if (x0) {
                if (t2 < 128) {
                    const int b = t2 >> 4, k = t2 & 15;
                    const short hh_ = tb(pxn);
                    xwr(&xhi[wb][0], rsh + b, k, hh_);
                    xwr(&xlo[wb][0], rsh + b, k, tb(pxn - fb(hh_)));
                }
            } else {
                const int b = t2 >> 6, u = t2 & 63;
                xwr(&xhi[wb][0], rsh + b, u, (short)(phn & 0xffff));
                xwr(&xlo[wb][0], rsh + b, u, (short)(phn >> 16));
            }
        }
        __syncthreads();

        if (t & 1) CxCur = CxNext;   // pair hand-off (wave-uniform)
        hin += SEQS;
        if (x0) xin += 16;
        hout += SEQS;
    }

    // ---- head: out = h2[T-1] @ Wout^T + bout ----
    if (do_head && tid < 7 * CB) {
        const int b = tid / 7, o = tid % 7;
        float a = bout[o];
        #pragma unroll
        for (int k = 0; k < HID; ++k)
            a = fmaf(hf[b * HID + k], Wout[o * HID + k], a);
        out[(b0 + b) * 7 + o] = a;
    }
}

extern "C" void kernel_launch(void* const* d_in, const int* in_sizes, int n_in,
                              void* d_out, int out_size, void* d_ws, size_t ws_size,
                              hipStream_t stream) {
    const float* x    = (const float*)d_in[0];
    const float* Wih0 = (const float*)d_in[1];
    const float* Whh0 = (const float*)d_in[2];
    const float* bih0 = (const float*)d_in[3];
    const float* bhh0 = (const float*)d_in[4];
    const float* Wih1 = (const float*)d_in[5];
    const float* Whh1 = (const float*)d_in[6];
    const float* bih1 = (const float*)d_in[7];
    const float* bhh1 = (const float*)d_in[8];
    const float* Wih2 = (const float*)d_in[9];
    const float* Whh2 = (const float*)d_in[10];
    const float* bih2 = (const float*)d_in[11];
    const float* bhh2 = (const float*)d_in[12];
    const float* Wout = (const float*)d_in[13];
    const float* bout = (const float*)d_in[14];
    float* out = (float*)d_out;
    unsigned* hseq = (unsigned*)d_ws;   // needs T*B*64*4 = 268,435,456 B

    const dim3 grid(BATCH / CB), blk(NTHR);
    lstm_layer<<<grid, blk, 0, stream>>>(x, hseq, Wih0, Whh0, bih0, bhh0,
                                         nullptr, nullptr, nullptr, 16, 1, 0);
    lstm_layer<<<grid, blk, 0, stream>>>(nullptr, hseq, Wih1, Whh1, bih1, bhh1,
                                         nullptr, nullptr, nullptr, HID, 1, 0);
    lstm_layer<<<grid, blk, 0, stream>>>(nullptr, hseq, Wih2, Whh2, bih2, bhh2,
                                         Wout, bout, out, HID, 0, 1);
}